// Round 2
// baseline (3495.259 us; speedup 1.0000x reference)
//
#include <hip/hip_runtime.h>
#include <cstdint>
#include <cstddef>

// Problem constants
#define B_   1024
#define L_   64
#define H_   512
#define NBLK 256

// Workspace layout (bytes). Total 12,061,696 (~11.5 MiB) — IDENTICAL to the
// proven R0 footprint (do not grow: ws_size may be exactly this).
//  WB  : transposed bf16 weights  BT_j[n][k]  (j0: 512x512, j1-3: 512x1024)
//  SB  : state buffers bf16 [layer j][parity], each in A-FRAGMENT TILE ORDER:
//        short index(row,k) = (row>>4)*8192 + (k>>3)*128 + (row&15)*8 + (k&7)
//  FLG : packed flags: u64 per (group g, block bi); byte w = rounds completed
//        by wave w of block bi in group g  (8 g x 32 blk x 8 B = 2048 B)
//  XCD : per-block XCC_ID table (256 x u32)
#define WB_OFF   0u
#define SB_OFF   3670016u
#define FLG_OFF  12058624u
#define XCD_OFF  12060672u

typedef __attribute__((ext_vector_type(8))) short short8;
typedef __attribute__((ext_vector_type(4))) float f32x4;
typedef unsigned long long u64;

__device__ __forceinline__ unsigned short f2bf(float f) {
  unsigned u = __float_as_uint(f);
  u += 0x7fffu + ((u >> 16) & 1u);   // RNE
  return (unsigned short)(u >> 16);
}

__device__ __forceinline__ float bf2f(unsigned short s) {
  return __uint_as_float(((unsigned)s) << 16);
}

__device__ __forceinline__ void async16(const void* g, void* l) {
  __builtin_amdgcn_global_load_lds(
      (const __attribute__((address_space(1))) void*)g,
      (__attribute__((address_space(3))) void*)l, 16, 0, 0);
}

// Device-coherent (agent-scope, relaxed) ops: L1-bypass, no fences.
__device__ __forceinline__ u64 cohload(const u64* p) {
  return __hip_atomic_load((u64*)p, __ATOMIC_RELAXED, __HIP_MEMORY_SCOPE_AGENT);
}
__device__ __forceinline__ void cohstore(u64* p, u64 v) {
  __hip_atomic_store(p, v, __ATOMIC_RELAXED, __HIP_MEMORY_SCOPE_AGENT);
}
__device__ __forceinline__ unsigned cohload32(const unsigned* p) {
  return __hip_atomic_load((unsigned*)p, __ATOMIC_RELAXED, __HIP_MEMORY_SCOPE_AGENT);
}
__device__ __forceinline__ void cohstore32(unsigned* p, unsigned v) {
  __hip_atomic_store(p, v, __ATOMIC_RELAXED, __HIP_MEMORY_SCOPE_AGENT);
}
__device__ __forceinline__ void cohstore8(unsigned char* p, unsigned char v) {
  __hip_atomic_store(p, v, __ATOMIC_RELAXED, __HIP_MEMORY_SCOPE_AGENT);
}

// ---------------------------------------------------------------------------
// Init: transpose+convert weights fp32->bf16 [N][K], zero SB + FLG + XCD.
// ---------------------------------------------------------------------------
__global__ __launch_bounds__(256) void init_kernel(
    const float* __restrict__ Wc, const float* __restrict__ Win_rest,
    char* __restrict__ ws)
{
  const unsigned bb = blockIdx.x;
  const int tid = threadIdx.x;
  if (bb < 448u) {
    __shared__ float tile[64][65];
    int m, tt;
    if (bb < 64u) { m = 0; tt = (int)bb; }
    else { m = 1 + (int)((bb - 64u) >> 7); tt = (int)((bb - 64u) & 127u); }
    const int Km = (m == 0) ? 512 : 1024;
    const int nkt = Km >> 6;
    const int tk = tt % nkt, tn = tt / nkt;
    const int k0 = tk << 6, n0 = tn << 6;
    const int rr = tid >> 4, cc = (tid & 15) << 2;
#pragma unroll
    for (int qq = 0; qq < 4; ++qq) {
      const int row = rr + qq * 16;     // local k
      const int kg = k0 + row;
      const float* src;
      if (m == 0)        src = Wc + (size_t)kg * 512 + n0 + cc;
      else if (kg < 512) src = Wc + ((size_t)m * 512 + kg) * 512 + n0 + cc;
      else               src = Win_rest + ((size_t)(m - 1) * 512 + (kg - 512)) * 512 + n0 + cc;
      const float4 v = *(const float4*)src;
      tile[row][cc + 0] = v.x; tile[row][cc + 1] = v.y;
      tile[row][cc + 2] = v.z; tile[row][cc + 3] = v.w;
    }
    __syncthreads();
    unsigned short* dst = (unsigned short*)(ws + WB_OFF);
    const size_t base = (m == 0) ? 0 : (size_t)262144 + (size_t)(m - 1) * 524288;
#pragma unroll
    for (int qq = 0; qq < 4; ++qq) {
      const int nl = rr + qq * 16;
      const int kl = (tid & 15) << 2;
      ushort4 o;
      o.x = f2bf(tile[kl + 0][nl]); o.y = f2bf(tile[kl + 1][nl]);
      o.z = f2bf(tile[kl + 2][nl]); o.w = f2bf(tile[kl + 3][nl]);
      *(ushort4*)(dst + base + (size_t)(n0 + nl) * Km + k0 + kl) = o;
    }
  } else {
    // zero SB (8,388,608 B) + FLG (2,048 B) + XCD (1,024 B) = 524,480 x 16 B
    f32x4* z = (f32x4*)(ws + SB_OFF);
    const unsigned idx = (bb - 448u) * 256u + (unsigned)tid;
    const f32x4 zero = {0.f, 0.f, 0.f, 0.f};
    for (unsigned u = idx; u < 524480u; u += 16384u) z[u] = zero;
  }
}

// ---------------------------------------------------------------------------
// Persistent kernel — wave-granular dataflow (packed byte flags).
//
// The 600-us baseline used a full 32-block group barrier per round: every
// round paid max-skew over 32 blocks plus a synchronized L2 A-load burst.
// This version removes the barrier. Dependency facts exploited:
//   * wave w of any block only ever READS wave-w rows (rowbase = bm0+w*16),
//     so flags are per-(block,wave): byte w of FLG64[g*32+bi] = rounds done.
//   * block (j,bn) round r needs: layer-j wave-w flags >= r (Ssrc, round r-1
//     writes visible; also proves sibling reads of round r-2 done);
//     layer-(j-1) wave-w flags >= r (Psrc) -- only needed from kstep 4 on,
//     so this wait sits AFTER ksteps 0..3 (the Ssrc-only quarter);
//   * WAR safety before overwriting parity (r&1): readers of the round-r-2
//     content must have finished round r-1.  Same-layer Ssrc readers are
//     covered by the producer wait; remaining readers are layer j+1 wave w
//     (j<3) or the logprob-owner block (g, 24+w) (j==3) -- waited AFTER the
//     whole K-loop, just before the epilogue stores (free in steady state).
//   * logprob lives in the 8 layer-3 blocks only (2 rows per wave), so the
//     rest of the graph is a chain, not a clique.
// No per-round __syncthreads: waves free-run; pipeline absorbs skew; layers
// stagger so A-load bursts spread over the XCD L2.
// ---------------------------------------------------------------------------
__global__ __launch_bounds__(512) void rnn_persistent(
    const int* __restrict__ x, const float* __restrict__ Win0,
    const float* __restrict__ bc, const float* __restrict__ Wout,
    const float* __restrict__ bout, char* __restrict__ ws,
    float* __restrict__ out)
{
  __shared__ short Bperm[16 * 64 * 64];     // 128 KiB persistent weight slice
  __shared__ short Cw[8][16 * 64];          // 16 KiB per-wave epilogue tile

  const int tid = threadIdx.x;
  const int wave = tid >> 6, lane = tid & 63;
  const int blk = (int)blockIdx.x;
  const int g  = blk & 7;            // row-group (XCD-affine under %8 heuristic)
  const int bi = blk >> 3;           // 0..31 within group
  const int j  = bi >> 3;            // layer 0..3
  const int bn = bi & 7;             // col-slice 0..7
  const int bm0 = g * 128;
  const int bn0 = bn * 64;
  const int bnc = bn0 >> 3;                 // first k-chunk our cols map to
  const int rowbase = bm0 + wave * 16;      // this wave's 16 batch rows
  const int rowblk  = rowbase >> 4;         // tile-row index in SB layout

  const unsigned short* WB = (const unsigned short*)(ws + WB_OFF);
  unsigned short* SB = (unsigned short*)(ws + SB_OFF);
  u64* FLG64 = (u64*)(ws + FLG_OFF);
  unsigned* XT = (unsigned*)(ws + XCD_OFF);

  const int Kc = (j == 0) ? 512 : 1024;
  const int nk = Kc >> 6;            // BK = 64: nk = 8 or 16

  const int q = lane >> 4, ln = lane & 15;
  const int swz = ln & 7;

  // ---- one-time: pin B slice in LDS (512 threads: one async16 per kk each)
  {
    const unsigned short* Wj = WB + ((j == 0) ? (size_t)0
                                   : ((size_t)262144 + (size_t)(j - 1) * 524288));
    const int nloc = tid >> 3;           // 0..63
    const int lchb = tid & 7;
    const int schunk = lchb ^ (nloc & 7);
    for (int kk = 0; kk < nk; ++kk) {
      async16(Wj + (size_t)(bn0 + nloc) * Kc + (kk << 6) + schunk * 8,
              &Bperm[kk * 4096 + nloc * 64 + lchb * 8]);
    }
  }

  // ---- XCD-affinity check: publish XCC_ID, ballot-poll all 32, verify.
  const unsigned myxcd = __builtin_amdgcn_s_getreg(6164);  // hwreg(20,0,4)
  if (tid == 0) cohstore32(&XT[blk], myxcd + 1u);
  unsigned xv = 1;
  {
    unsigned spins = 0;
    for (;;) {
      xv = 1;
      if (lane < 32) xv = cohload32(&XT[lane * 8 + g]);
      if (__ballot(xv != 0) == ~0ull) break;
      __builtin_amdgcn_s_sleep(2);
      if (++spins > (1u << 20)) break;
    }
  }
  const unsigned xv0 = __shfl(xv, 0);
  const bool fast = (__ballot(lane >= 32 || xv == xv0) == ~0ull);
  __syncthreads();   // also drains this wave's B staging loads

  // ---- hoist per-round-invariant weights into registers
  float wout0[8], wout1[8];
  float bo0 = 0.f, bo1 = 0.f;
  if (j == 3) {
#pragma unroll
    for (int i = 0; i < 8; ++i) {
      const int n = lane * 8 + i;
      wout0[i] = Wout[n * 2 + 0];
      wout1[i] = Wout[n * 2 + 1];
    }
    bo0 = bout[0]; bo1 = bout[1];
  }
  float bcv[4], w0v[4], w1v[4];
#pragma unroll
  for (int nt = 0; nt < 4; ++nt) {
    const int col = bn0 + ln + nt * 16;
    bcv[nt] = bc[j * H_ + col];
    w0v[nt] = Win0[col];            // xprev == 0 row
    w1v[nt] = Win0[H_ + col];       // xprev == 1 row
  }

  float runLP0 = 0.f, runLP1 = 0.f;

  const int gbase = g * 32;          // u64 flag index base for this group

  // lanes 0..7 poll FLG64[gbase+blk0+lane]; bytes byteA (and byteB if >=0)
  // must reach target.  Values <= 68 so u8 compare is exact.
  auto waitrow = [&](int blk0, int byteA, int byteB, unsigned target) {
    unsigned spins = 0;
    for (;;) {
      bool ok = true;
      if (lane < 8) {
        const u64 v = cohload(&FLG64[gbase + blk0 + lane]);
        ok = (((v >> (8 * byteA)) & 0xffu) >= target);
        if (byteB >= 0) ok = ok && (((v >> (8 * byteB)) & 0xffu) >= target);
      }
      if (__ballot(ok) == ~0ull) break;
      __builtin_amdgcn_s_sleep(1);
      if (++spins > (1u << 18)) break;   // failsafe: wrong-answer beats hang
    }
    if (!fast) __builtin_amdgcn_fence(__ATOMIC_ACQUIRE, "agent");
  };
  // all 8 bytes of one block's u64 must reach target (lane i checks byte i)
  auto waitall = [&](int blkb, unsigned target) {
    unsigned spins = 0;
    for (;;) {
      bool ok = true;
      if (lane < 8) {
        const u64 v = cohload(&FLG64[gbase + blkb]);
        ok = (((v >> (8 * lane)) & 0xffu) >= target);
      }
      if (__ballot(ok) == ~0ull) break;
      __builtin_amdgcn_s_sleep(1);
      if (++spins > (1u << 18)) break;
    }
    if (!fast) __builtin_amdgcn_fence(__ATOMIC_ACQUIRE, "agent");
  };

#pragma clang loop unroll(disable)
  for (int r = 0; r <= 67; ++r) {
    const int pprev = (r + 1) & 1, pcur = r & 1;
    const int t = r - j;
    const bool active = (t >= 0 && t <= 63);
    const bool dolp = (j == 3) && (r >= 4);   // logprob for tl = r-4
    const unsigned tgt = (unsigned)r;

    // ---- producer wait: same-layer wave-w flags >= r (Ssrc round r-1 writes
    // visible). j3 additionally needs sibling wave-bn flags (logprob rows) --
    // merged into the same u64 polls.
    if (j == 3) {
      if (active || dolp) waitrow(24, wave, bn, tgt);
    } else if (active) {
      waitrow(j * 8, wave, -1, tgt);
    }

    const unsigned short* Ssrc = SB + (size_t)(j * 2 + pprev) * (B_ * H_);
    const unsigned short* Psrc = (j > 0)
        ? SB + (size_t)((j - 1) * 2 + pprev) * (B_ * H_) : (const unsigned short*)0;
    unsigned short* Dst = SB + (size_t)(j * 2 + pcur) * (B_ * H_);

    u64 s0[2][2], s1[2][2], s2[2][2], s3[2][2];
    auto loadTo = [&](int kk, u64 (&st)[2][2]) {
      const int k0 = kk << 6;
      const unsigned short* Asrc; int ak0;
      if (k0 < 512) { Asrc = Ssrc; ak0 = k0; } else { Asrc = Psrc; ak0 = k0 - 512; }
      const int kc0 = ak0 >> 3;
#pragma unroll
      for (int s = 0; s < 2; ++s) {
        const u64* gp = (const u64*)(Asrc + (size_t)rowblk * 8192
                                     + (size_t)(kc0 + s * 4 + q) * 128 + ln * 8);
        st[s][0] = cohload(gp);
        st[s][1] = cohload(gp + 1);
      }
    };
    f32x4 accA[4] = {};
    f32x4 accB[4] = {};
    auto kstep = [&](int kk, u64 (&st)[2][2]) {
      short8 af0, af1;
      __builtin_memcpy(&af0, &st[0][0], 16);
      __builtin_memcpy(&af1, &st[1][0], 16);
      if (kk + 4 < nk) loadTo(kk + 4, st);    // refill same set, 4 ahead
      const short* Bb = &Bperm[kk * 4096];
#pragma unroll
      for (int nt = 0; nt < 4; ++nt) {
        const short8 b0 = *(const short8*)(Bb + (nt * 16 + ln) * 64
                                           + (q ^ swz) * 8);
        accA[nt] = __builtin_amdgcn_mfma_f32_16x16x32_bf16(af0, b0, accA[nt], 0, 0, 0);
      }
#pragma unroll
      for (int nt = 0; nt < 4; ++nt) {
        const short8 b1 = *(const short8*)(Bb + (nt * 16 + ln) * 64
                                           + ((4 | q) ^ swz) * 8);
        accB[nt] = __builtin_amdgcn_mfma_f32_16x16x32_bf16(af1, b1, accB[nt], 0, 0, 0);
      }
    };

    if (active) { loadTo(0, s0); loadTo(1, s1); loadTo(2, s2); loadTo(3, s3); }

    // ---- logprob (layer-3 blocks only): rows bm0+bn*16+{2*wave, 2*wave+1},
    // reads sibling wave-bn output of round r-1 (gated by waitrow above).
    // VALU work overlaps the A-load latency just issued.
    if (dolp) {
      const int tl = r - 4;
      const unsigned short* h3 = SB + (size_t)(3 * 2 + pprev) * (B_ * H_);
      const int browA = bm0 + bn * 16 + wave * 2;
      const int browB = browA + 1;
      const u64* hpA = (const u64*)(h3 + (size_t)(browA >> 4) * 8192
                                    + (size_t)(browA & 15) * 8 + (size_t)lane * 128);
      const u64* hpB = (const u64*)(h3 + (size_t)(browB >> 4) * 8192
                                    + (size_t)(browB & 15) * 8 + (size_t)lane * 128);
      const u64 a0 = cohload(hpA), a1 = cohload(hpA + 1);
      const u64 b0 = cohload(hpB), b1 = cohload(hpB + 1);
      float zA0 = 0.f, zA1 = 0.f, zB0 = 0.f, zB1 = 0.f;
#pragma unroll
      for (int i = 0; i < 8; ++i) {
        const u64 ha = (i < 4) ? a0 : a1;
        const u64 hb = (i < 4) ? b0 : b1;
        const float fa = bf2f((unsigned short)((ha >> (16 * (i & 3))) & 0xffffu));
        const float fb = bf2f((unsigned short)((hb >> (16 * (i & 3))) & 0xffffu));
        zA0 = fmaf(fa, wout0[i], zA0); zA1 = fmaf(fa, wout1[i], zA1);
        zB0 = fmaf(fb, wout0[i], zB0); zB1 = fmaf(fb, wout1[i], zB1);
      }
#pragma unroll
      for (int off = 32; off > 0; off >>= 1) {
        zA0 += __shfl_down(zA0, off); zA1 += __shfl_down(zA1, off);
        zB0 += __shfl_down(zB0, off); zB1 += __shfl_down(zB1, off);
      }
      if (lane == 0) {
        {
          const float z0 = zA0 + bo0, z1 = zA1 + bo1;
          const float mx = fmaxf(z0, z1), mn = fminf(z0, z1);
          const float lse = mx + log1pf(__expf(mn - mx));
          const int xt = x[browA * L_ + tl];
          float lp = ((xt == 0) ? z0 : z1) - lse;
          if (!(lp == lp)) lp = -35.0f;
          runLP0 += lp;
          if (tl == 63) out[browA] = 0.5f * runLP0;   // LOG_PROB_FACTOR
        }
        {
          const float z0 = zB0 + bo0, z1 = zB1 + bo1;
          const float mx = fmaxf(z0, z1), mn = fminf(z0, z1);
          const float lse = mx + log1pf(__expf(mn - mx));
          const int xt = x[browB * L_ + tl];
          float lp = ((xt == 0) ? z0 : z1) - lse;
          if (!(lp == lp)) lp = -35.0f;
          runLP1 += lp;
          if (tl == 63) out[browB] = 0.5f * runLP1;
        }
      }
    }

    // ---- GEMM cell (t, j): wave-local, sync-free, rolled x4 k-loop.
    if (active) {
      // ksteps 0..3 touch only Ssrc (k0 <= 448) -- run before the Psrc wait.
      kstep(0, s0); kstep(1, s1); kstep(2, s2); kstep(3, s3);
      if (j > 0) waitrow((j - 1) * 8, wave, -1, tgt);   // Psrc ready
      for (int kk = 4; kk < nk; kk += 4) {
        kstep(kk + 0, s0);
        kstep(kk + 1, s1);
        kstep(kk + 2, s2);
        kstep(kk + 3, s3);
      }

      // ---- WAR safety (late): remaining readers of our round r-2 output
      // must have finished round r-1 before we overwrite parity pcur.
      if (j < 3) waitrow((j + 1) * 8, wave, -1, tgt);
      else       waitall(24 + wave, tgt);    // logprob owner block, all waves

      // per-wave epilogue: bias (+Win0) + elu -> swizzled Ctile -> stores
      short* Ctile = &Cw[wave][0];
#pragma unroll
      for (int i = 0; i < 4; ++i) {
        const int lr = q * 4 + i;        // local row 0..15
        const int brow = rowbase + lr;
        int xprev = 0;
        if (j == 0 && t > 0) xprev = x[brow * L_ + (t - 1)];
#pragma unroll
        for (int nt = 0; nt < 4; ++nt) {
          float pre = accA[nt][i] + accB[nt][i] + bcv[nt];
          if (j == 0 && t > 0) pre += (xprev ? w1v[nt] : w0v[nt]);
          const float h = (pre > 0.f) ? pre : (__expf(pre) - 1.0f);
          const int chunkcol = nt * 2 + (ln >> 3);
          Ctile[lr * 64 + (chunkcol ^ (lr & 7)) * 8 + (ln & 7)] = (short)f2bf(h);
        }
      }
      // write out in SB tile order, fully coalesced (1 KB per instruction).
      // same-wave DS in-order: Ctile readback needs no barrier.
      const int lrs = ln;                 // row 0..15
#pragma unroll
      for (int it = 0; it < 2; ++it) {
        const int ch = q + it * 4;        // our k-chunk 0..7 (cols bn0+ch*8)
        const u64* p = (const u64*)(Ctile + lrs * 64 + (ch ^ (lrs & 7)) * 8);
        const u64 d0 = p[0], d1 = p[1];
        u64* gdst = (u64*)(Dst + (size_t)rowblk * 8192
                           + (size_t)(bnc + ch) * 128 + lrs * 8);
        if (fast) {                      // plain write-back: stays in XCD L2
          gdst[0] = d0;
          gdst[1] = d1;
        } else {                         // coherent write-through
          cohstore(gdst, d0);
          cohstore(gdst + 1, d1);
        }
      }

      if (!fast) __builtin_amdgcn_fence(__ATOMIC_RELEASE, "agent");
      asm volatile("s_waitcnt vmcnt(0)" ::: "memory");   // our stores in L2
    }

    // ---- publish: this wave completed round r (reads done, writes visible)
    if (lane == 0) {
      unsigned char* fb = (unsigned char*)&FLG64[gbase + bi];
      cohstore8(fb + wave, (unsigned char)(r + 1));
    }

    // nothing consumes layer-j (j<3) flags beyond round 63+j -> exit early
    if (j < 3 && r >= 63 + j) break;
  }
}

// ---------------------------------------------------------------------------
extern "C" void kernel_launch(void* const* d_in, const int* in_sizes, int n_in,
                              void* d_out, int out_size, void* d_ws, size_t ws_size,
                              hipStream_t stream) {
  const int*   x        = (const int*)d_in[0];
  const float* Win0     = (const float*)d_in[1];
  const float* Win_rest = (const float*)d_in[2];
  const float* Wc       = (const float*)d_in[3];
  const float* bc       = (const float*)d_in[4];
  const float* Wout     = (const float*)d_in[5];
  const float* bout     = (const float*)d_in[6];
  float* out = (float*)d_out;
  char*  ws  = (char*)d_ws;

  init_kernel<<<512, 256, 0, stream>>>(Wc, Win_rest, ws);
  rnn_persistent<<<NBLK, 512, 0, stream>>>(x, Win0, bc, Wout, bout, ws, out);
}

// Round 3
// 744.618 us; speedup vs baseline: 4.6940x; 4.6940x over previous
//
#include <hip/hip_runtime.h>
#include <cstdint>
#include <cstddef>

// Problem constants
#define B_   1024
#define L_   64
#define H_   512
#define NBLK 256

// Workspace layout (bytes). Total 12,061,696 (~11.5 MiB) — IDENTICAL to the
// proven R0 footprint (do not grow).
//  WB  : transposed bf16 weights  BT_j[n][k]  (j0: 512x512, j1-3: 512x1024)
//  SB  : state buffers bf16 [layer j][parity], each in A-FRAGMENT TILE ORDER:
//        short index(row,k) = (row>>4)*8192 + (k>>3)*128 + (row&15)*8 + (k&7)
//  BAR : SLOT array: 8 groups x 32 blocks x u32 (one u32 per block)
//  XCD : per-block XCC_ID table (256 x u32)
#define WB_OFF   0u
#define SB_OFF   3670016u
#define BAR_OFF  12058624u
#define XCD_OFF  12060672u

typedef __attribute__((ext_vector_type(8))) short short8;
typedef __attribute__((ext_vector_type(4))) float f32x4;
typedef unsigned long long u64;

__device__ __forceinline__ unsigned short f2bf(float f) {
  unsigned u = __float_as_uint(f);
  u += 0x7fffu + ((u >> 16) & 1u);   // RNE
  return (unsigned short)(u >> 16);
}

__device__ __forceinline__ float bf2f(unsigned short s) {
  return __uint_as_float(((unsigned)s) << 16);
}

__device__ __forceinline__ void async16(const void* g, void* l) {
  __builtin_amdgcn_global_load_lds(
      (const __attribute__((address_space(1))) void*)g,
      (__attribute__((address_space(3))) void*)l, 16, 0, 0);
}

// Device-coherent (agent-scope, relaxed) ops: L1-bypass, no fences.
__device__ __forceinline__ u64 cohload(const u64* p) {
  return __hip_atomic_load((u64*)p, __ATOMIC_RELAXED, __HIP_MEMORY_SCOPE_AGENT);
}
__device__ __forceinline__ void cohstore(u64* p, u64 v) {
  __hip_atomic_store(p, v, __ATOMIC_RELAXED, __HIP_MEMORY_SCOPE_AGENT);
}
__device__ __forceinline__ unsigned cohload32(const unsigned* p) {
  return __hip_atomic_load((unsigned*)p, __ATOMIC_RELAXED, __HIP_MEMORY_SCOPE_AGENT);
}
__device__ __forceinline__ void cohstore32(unsigned* p, unsigned v) {
  __hip_atomic_store(p, v, __ATOMIC_RELAXED, __HIP_MEMORY_SCOPE_AGENT);
}

// control-only barrier: no vmcnt drain (prefetches stay in flight)
#define CTRLBAR() do { asm volatile("" ::: "memory"); \
                       __builtin_amdgcn_s_barrier();  \
                       asm volatile("" ::: "memory"); } while (0)

// ---------------------------------------------------------------------------
// Init: transpose+convert weights fp32->bf16 [N][K], zero SB + BAR + XCD.
// ---------------------------------------------------------------------------
__global__ __launch_bounds__(256) void init_kernel(
    const float* __restrict__ Wc, const float* __restrict__ Win_rest,
    char* __restrict__ ws)
{
  const unsigned bb = blockIdx.x;
  const int tid = threadIdx.x;
  if (bb < 448u) {
    __shared__ float tile[64][65];
    int m, tt;
    if (bb < 64u) { m = 0; tt = (int)bb; }
    else { m = 1 + (int)((bb - 64u) >> 7); tt = (int)((bb - 64u) & 127u); }
    const int Km = (m == 0) ? 512 : 1024;
    const int nkt = Km >> 6;
    const int tk = tt % nkt, tn = tt / nkt;
    const int k0 = tk << 6, n0 = tn << 6;
    const int rr = tid >> 4, cc = (tid & 15) << 2;
#pragma unroll
    for (int qq = 0; qq < 4; ++qq) {
      const int row = rr + qq * 16;     // local k
      const int kg = k0 + row;
      const float* src;
      if (m == 0)        src = Wc + (size_t)kg * 512 + n0 + cc;
      else if (kg < 512) src = Wc + ((size_t)m * 512 + kg) * 512 + n0 + cc;
      else               src = Win_rest + ((size_t)(m - 1) * 512 + (kg - 512)) * 512 + n0 + cc;
      const float4 v = *(const float4*)src;
      tile[row][cc + 0] = v.x; tile[row][cc + 1] = v.y;
      tile[row][cc + 2] = v.z; tile[row][cc + 3] = v.w;
    }
    __syncthreads();
    unsigned short* dst = (unsigned short*)(ws + WB_OFF);
    const size_t base = (m == 0) ? 0 : (size_t)262144 + (size_t)(m - 1) * 524288;
#pragma unroll
    for (int qq = 0; qq < 4; ++qq) {
      const int nl = rr + qq * 16;
      const int kl = (tid & 15) << 2;
      ushort4 o;
      o.x = f2bf(tile[kl + 0][nl]); o.y = f2bf(tile[kl + 1][nl]);
      o.z = f2bf(tile[kl + 2][nl]); o.w = f2bf(tile[kl + 3][nl]);
      *(ushort4*)(dst + base + (size_t)(n0 + nl) * Km + k0 + kl) = o;
    }
  } else {
    // zero SB (8,388,608 B) + BAR (2,048 B) + XCD (1,024 B) = 524,480 x 16 B
    f32x4* z = (f32x4*)(ws + SB_OFF);
    const unsigned idx = (bb - 448u) * 256u + (unsigned)tid;
    const f32x4 zero = {0.f, 0.f, 0.f, 0.f};
    for (unsigned u = idx; u < 524480u; u += 16384u) z[u] = zero;
  }
}

// ---------------------------------------------------------------------------
// Persistent kernel — R0 lockstep structure + NARROW PLACED WAITS.
//
// R0 (603 us) synchronized all 32 blocks of a group every round (full-group
// max-skew + synchronized L2 burst).  R2's free-running per-wave flags
// collapsed (poll-storm on the flag cachelines: 24x more pollers, per-lane
// atomic loads).  This version keeps R0's contention profile EXACTLY (one
// polling wave per block, one u32 slot store per block-round) but waits only
// on true dependencies, at the latest correct point:
//   [P] producer: layer-j slots >= r, at round start  (Ssrc = round r-1
//       output of the 8 layer-j blocks; also covers all WAR for j==3 since
//       logprob readers are the layer-3 blocks themselves)
//   [Q] Psrc: layer-(j-1) slots >= r, AFTER ksteps 0..3 (k<512 reads Ssrc
//       only) -- the handoff hides under 4 ksteps of MFMA+prefetch
//   [W] WAR: layer-(j+1) slots >= r, AFTER the K-loop and the Ctile
//       epilogue, right before the global stores -- free in steady state
// Logprob moved to the 8 layer-3 blocks (2 rows/wave) so the other 24 blocks
// do not depend on layer 3 at all -- this is what breaks the 32-clique.
// Dependency graph finish(j,r) <- finish(j+-1|j, r-1): acyclic, no deadlock.
// [P]/[Q]/[W] use raw s_barrier (control only, no vmcnt drain); the publish
// keeps R0's __syncthreads (store drain) + tid0 slot store.
// ---------------------------------------------------------------------------
__global__ __launch_bounds__(512) void rnn_persistent(
    const int* __restrict__ x, const float* __restrict__ Win0,
    const float* __restrict__ bc, const float* __restrict__ Wout,
    const float* __restrict__ bout, char* __restrict__ ws,
    float* __restrict__ out)
{
  __shared__ short Bperm[16 * 64 * 64];     // 128 KiB persistent weight slice
  __shared__ short Cw[8][16 * 64];          // 16 KiB per-wave epilogue tile

  const int tid = threadIdx.x;
  const int wave = tid >> 6, lane = tid & 63;
  const int blk = (int)blockIdx.x;
  const int g  = blk & 7;            // row-group (XCD-affine under %8 heuristic)
  const int bi = blk >> 3;           // 0..31 within group
  const int j  = bi >> 3;            // layer 0..3
  const int bn = bi & 7;             // col-slice 0..7
  const int bm0 = g * 128;
  const int bn0 = bn * 64;
  const int bnc = bn0 >> 3;                 // first k-chunk our cols map to
  const int rowbase = bm0 + wave * 16;      // this wave's 16 batch rows
  const int rowblk  = rowbase >> 4;         // tile-row index in SB layout

  const unsigned short* WB = (const unsigned short*)(ws + WB_OFF);
  unsigned short* SB = (unsigned short*)(ws + SB_OFF);
  unsigned* SLOT = (unsigned*)(ws + BAR_OFF);
  unsigned* XT = (unsigned*)(ws + XCD_OFF);

  const int Kc = (j == 0) ? 512 : 1024;
  const int nk = Kc >> 6;            // BK = 64: nk = 8 or 16

  const int q = lane >> 4, ln = lane & 15;
  const int swz = ln & 7;

  // ---- one-time: pin B slice in LDS (512 threads: one async16 per kk each)
  {
    const unsigned short* Wj = WB + ((j == 0) ? (size_t)0
                                   : ((size_t)262144 + (size_t)(j - 1) * 524288));
    const int nloc = tid >> 3;           // 0..63
    const int lchb = tid & 7;
    const int schunk = lchb ^ (nloc & 7);
    for (int kk = 0; kk < nk; ++kk) {
      async16(Wj + (size_t)(bn0 + nloc) * Kc + (kk << 6) + schunk * 8,
              &Bperm[kk * 4096 + nloc * 64 + lchb * 8]);
    }
  }

  // ---- XCD-affinity check: publish XCC_ID, ballot-poll all 32, verify.
  const unsigned myxcd = __builtin_amdgcn_s_getreg(6164);  // hwreg(20,0,4)
  if (tid == 0) cohstore32(&XT[blk], myxcd + 1u);
  unsigned xv = 1;
  {
    unsigned spins = 0;
    for (;;) {
      xv = 1;
      if (lane < 32) xv = cohload32(&XT[lane * 8 + g]);
      if (__ballot(xv != 0) == ~0ull) break;
      __builtin_amdgcn_s_sleep(2);
      if (++spins > (1u << 20)) break;
    }
  }
  const unsigned xv0 = __shfl(xv, 0);
  const bool fast = (__ballot(lane >= 32 || xv == xv0) == ~0ull);
  __syncthreads();   // also drains this wave's B staging loads

  // ---- hoist per-round-invariant weights into registers
  float wout0[8], wout1[8];
  float bo0 = 0.f, bo1 = 0.f;
  if (j == 3) {
#pragma unroll
    for (int i = 0; i < 8; ++i) {
      const int n = lane * 8 + i;
      wout0[i] = Wout[n * 2 + 0];
      wout1[i] = Wout[n * 2 + 1];
    }
    bo0 = bout[0]; bo1 = bout[1];
  }
  float bcv[4], w0v[4], w1v[4];
#pragma unroll
  for (int nt = 0; nt < 4; ++nt) {
    const int col = bn0 + ln + nt * 16;
    bcv[nt] = bc[j * H_ + col];
    w0v[nt] = Win0[col];            // xprev == 0 row
    w1v[nt] = Win0[H_ + col];       // xprev == 1 row
  }

  float runLP0 = 0.f, runLP1 = 0.f;

  // wave 0 polls 8 slots of one layer until all reach target (<= 68)
  auto poll8 = [&](int slot0, unsigned target) {
    unsigned spins = 0;
    for (;;) {
      unsigned v = target;
      if (lane < 8) v = cohload32(&SLOT[g * 32 + slot0 + lane]);
      if (__ballot(v >= target) == ~0ull) break;
      __builtin_amdgcn_s_sleep(1);
      if (++spins > (1u << 18)) break;   // failsafe: wrong-answer beats hang
    }
    if (!fast) __builtin_amdgcn_fence(__ATOMIC_ACQUIRE, "agent");
  };

#pragma clang loop unroll(disable)
  for (int r = 0; r <= 67; ++r) {
    const int pprev = (r + 1) & 1, pcur = r & 1;
    const int t = r - j;
    const bool active = (t >= 0 && t <= 63);
    const bool dolp = (j == 3) && (r >= 4);   // logprob for tl = r-4
    const unsigned tgt = (unsigned)r;

    // ---- [P] producer wait: layer-j blocks finished round r-1.
    const bool needP = (j == 3) ? (active || dolp) : active;
    if (needP) {
      if (wave == 0) poll8(j * 8, tgt);
      CTRLBAR();
    }

    const unsigned short* Ssrc = SB + (size_t)(j * 2 + pprev) * (B_ * H_);
    const unsigned short* Psrc = (j > 0)
        ? SB + (size_t)((j - 1) * 2 + pprev) * (B_ * H_) : (const unsigned short*)0;
    unsigned short* Dst = SB + (size_t)(j * 2 + pcur) * (B_ * H_);

    u64 s0[2][2], s1[2][2], s2[2][2], s3[2][2];
    auto loadTo = [&](int kk, u64 (&st)[2][2]) {
      const int k0 = kk << 6;
      const unsigned short* Asrc; int ak0;
      if (k0 < 512) { Asrc = Ssrc; ak0 = k0; } else { Asrc = Psrc; ak0 = k0 - 512; }
      const int kc0 = ak0 >> 3;
#pragma unroll
      for (int s = 0; s < 2; ++s) {
        const u64* gp = (const u64*)(Asrc + (size_t)rowblk * 8192
                                     + (size_t)(kc0 + s * 4 + q) * 128 + ln * 8);
        st[s][0] = cohload(gp);
        st[s][1] = cohload(gp + 1);
      }
    };
    f32x4 accA[4] = {};
    f32x4 accB[4] = {};
    auto kstep = [&](int kk, u64 (&st)[2][2]) {
      short8 af0, af1;
      __builtin_memcpy(&af0, &st[0][0], 16);
      __builtin_memcpy(&af1, &st[1][0], 16);
      if (kk + 4 < nk) loadTo(kk + 4, st);    // refill same set, 4 ahead
      const short* Bb = &Bperm[kk * 4096];
#pragma unroll
      for (int nt = 0; nt < 4; ++nt) {
        const short8 b0 = *(const short8*)(Bb + (nt * 16 + ln) * 64
                                           + (q ^ swz) * 8);
        accA[nt] = __builtin_amdgcn_mfma_f32_16x16x32_bf16(af0, b0, accA[nt], 0, 0, 0);
      }
#pragma unroll
      for (int nt = 0; nt < 4; ++nt) {
        const short8 b1 = *(const short8*)(Bb + (nt * 16 + ln) * 64
                                           + ((4 | q) ^ swz) * 8);
        accB[nt] = __builtin_amdgcn_mfma_f32_16x16x32_bf16(af1, b1, accB[nt], 0, 0, 0);
      }
    };

    if (active) { loadTo(0, s0); loadTo(1, s1); loadTo(2, s2); loadTo(3, s3); }

    // ---- logprob (layer-3 blocks only): rows bm0+bn*16+{2*wave, 2*wave+1},
    // reads h3 of round r-1 (gated by [P]). VALU overlaps A-load latency.
    if (dolp) {
      const int tl = r - 4;
      const unsigned short* h3 = SB + (size_t)(3 * 2 + pprev) * (B_ * H_);
      const int browA = bm0 + bn * 16 + wave * 2;
      const int browB = browA + 1;
      const u64* hpA = (const u64*)(h3 + (size_t)(browA >> 4) * 8192
                                    + (size_t)(browA & 15) * 8 + (size_t)lane * 128);
      const u64* hpB = (const u64*)(h3 + (size_t)(browB >> 4) * 8192
                                    + (size_t)(browB & 15) * 8 + (size_t)lane * 128);
      const u64 a0 = cohload(hpA), a1 = cohload(hpA + 1);
      const u64 b0 = cohload(hpB), b1 = cohload(hpB + 1);
      float zA0 = 0.f, zA1 = 0.f, zB0 = 0.f, zB1 = 0.f;
#pragma unroll
      for (int i = 0; i < 8; ++i) {
        const u64 ha = (i < 4) ? a0 : a1;
        const u64 hb = (i < 4) ? b0 : b1;
        const float fa = bf2f((unsigned short)((ha >> (16 * (i & 3))) & 0xffffu));
        const float fb = bf2f((unsigned short)((hb >> (16 * (i & 3))) & 0xffffu));
        zA0 = fmaf(fa, wout0[i], zA0); zA1 = fmaf(fa, wout1[i], zA1);
        zB0 = fmaf(fb, wout0[i], zB0); zB1 = fmaf(fb, wout1[i], zB1);
      }
#pragma unroll
      for (int off = 32; off > 0; off >>= 1) {
        zA0 += __shfl_down(zA0, off); zA1 += __shfl_down(zA1, off);
        zB0 += __shfl_down(zB0, off); zB1 += __shfl_down(zB1, off);
      }
      if (lane == 0) {
        {
          const float z0 = zA0 + bo0, z1 = zA1 + bo1;
          const float mx = fmaxf(z0, z1), mn = fminf(z0, z1);
          const float lse = mx + log1pf(__expf(mn - mx));
          const int xt = x[browA * L_ + tl];
          float lp = ((xt == 0) ? z0 : z1) - lse;
          if (!(lp == lp)) lp = -35.0f;
          runLP0 += lp;
          if (tl == 63) out[browA] = 0.5f * runLP0;   // LOG_PROB_FACTOR
        }
        {
          const float z0 = zB0 + bo0, z1 = zB1 + bo1;
          const float mx = fmaxf(z0, z1), mn = fminf(z0, z1);
          const float lse = mx + log1pf(__expf(mn - mx));
          const int xt = x[browB * L_ + tl];
          float lp = ((xt == 0) ? z0 : z1) - lse;
          if (!(lp == lp)) lp = -35.0f;
          runLP1 += lp;
          if (tl == 63) out[browB] = 0.5f * runLP1;
        }
      }
    }

    // ---- GEMM cell (t, j): wave-local k-loop, narrow waits between phases.
    if (active) {
      // ksteps 0..3 touch only Ssrc (k0 <= 448): run before the Psrc wait.
      kstep(0, s0); kstep(1, s1); kstep(2, s2); kstep(3, s3);
      if (j > 0) {                       // [Q] Psrc handoff, hidden under MFMA
        if (wave == 0) poll8((j - 1) * 8, tgt);
        CTRLBAR();
      }
      for (int kk = 4; kk < nk; kk += 4) {
        kstep(kk + 0, s0);
        kstep(kk + 1, s1);
        kstep(kk + 2, s2);
        kstep(kk + 3, s3);
      }

      // per-wave epilogue: bias (+Win0) + elu -> swizzled Ctile (LDS only)
      short* Ctile = &Cw[wave][0];
#pragma unroll
      for (int i = 0; i < 4; ++i) {
        const int lr = q * 4 + i;        // local row 0..15
        const int brow = rowbase + lr;
        int xprev = 0;
        if (j == 0 && t > 0) xprev = x[brow * L_ + (t - 1)];
#pragma unroll
        for (int nt = 0; nt < 4; ++nt) {
          float pre = accA[nt][i] + accB[nt][i] + bcv[nt];
          if (j == 0 && t > 0) pre += (xprev ? w1v[nt] : w0v[nt]);
          const float h = (pre > 0.f) ? pre : (__expf(pre) - 1.0f);
          const int chunkcol = nt * 2 + (ln >> 3);
          Ctile[lr * 64 + (chunkcol ^ (lr & 7)) * 8 + (ln & 7)] = (short)f2bf(h);
        }
      }

      // ---- [W] WAR wait (j<3): layer j+1 finished its round-(r-1) reads of
      // the parity we are about to overwrite.  j==3 is covered by [P].
      if (j < 3) {
        if (wave == 0) poll8((j + 1) * 8, tgt);
        CTRLBAR();
      }

      // write out in SB tile order, fully coalesced (1 KB per instruction).
      const int lrs = ln;                 // row 0..15
#pragma unroll
      for (int it = 0; it < 2; ++it) {
        const int ch = q + it * 4;        // our k-chunk 0..7 (cols bn0+ch*8)
        const u64* p = (const u64*)(Ctile + lrs * 64 + (ch ^ (lrs & 7)) * 8);
        const u64 d0 = p[0], d1 = p[1];
        u64* gdst = (u64*)(Dst + (size_t)rowblk * 8192
                           + (size_t)(bnc + ch) * 128 + lrs * 8);
        if (fast) {                      // plain write-back: stays in XCD L2
          gdst[0] = d0;
          gdst[1] = d1;
        } else {                         // coherent write-through
          cohstore(gdst, d0);
          cohstore(gdst + 1, d1);
        }
      }
    }

    // ---- publish: all waves' stores drained, then one slot store per block
    if (!fast) __builtin_amdgcn_fence(__ATOMIC_RELEASE, "agent");
    __syncthreads();                   // drains vmcnt for every wave
    if (tid == 0) cohstore32(&SLOT[g * 32 + bi], (unsigned)(r + 1));

    // nothing consumes layer-j (j<3) slots beyond target 64+j -> exit early
    if (j < 3 && r >= 63 + j) break;
  }
}

// ---------------------------------------------------------------------------
extern "C" void kernel_launch(void* const* d_in, const int* in_sizes, int n_in,
                              void* d_out, int out_size, void* d_ws, size_t ws_size,
                              hipStream_t stream) {
  const int*   x        = (const int*)d_in[0];
  const float* Win0     = (const float*)d_in[1];
  const float* Win_rest = (const float*)d_in[2];
  const float* Wc       = (const float*)d_in[3];
  const float* bc       = (const float*)d_in[4];
  const float* Wout     = (const float*)d_in[5];
  const float* bout     = (const float*)d_in[6];
  float* out = (float*)d_out;
  char*  ws  = (char*)d_ws;

  init_kernel<<<512, 256, 0, stream>>>(Wc, Win_rest, ws);
  rnn_persistent<<<NBLK, 512, 0, stream>>>(x, Win0, bc, Wout, bout, ws, out);
}